// Round 10
// baseline (340.450 us; speedup 1.0000x reference)
//
#include <hip/hip_runtime.h>
#include <hip/hip_bf16.h>
#include <stdint.h>

// B=32, S=4096, ENC=512, DEC=512
// out = softmax_s( sum_d tanh( enc @ W_e^T + dh @ W_h^T + b ) * v )

typedef __attribute__((ext_vector_type(8))) short short8;
typedef __attribute__((ext_vector_type(4))) float f32x4;

static __device__ __forceinline__ short8 cvt8(float4 a, float4 b) {
    // 4x v_cvt_pk_bf16_f32 (RNE)
    union { short8 s; __hip_bfloat162 h[4]; } u;
    u.h[0] = __float22bfloat162_rn(float2{a.x, a.y});
    u.h[1] = __float22bfloat162_rn(float2{a.z, a.w});
    u.h[2] = __float22bfloat162_rn(float2{b.x, b.y});
    u.h[3] = __float22bfloat162_rn(float2{b.z, b.w});
    return u.s;
}

static __device__ __forceinline__ float tanh_fast(float x) {
    // tanh(x) = 1 - 2/(exp(2x)+1); overflow->+1, underflow->-1 (both correct)
    return 1.0f - 2.0f / (__expf(2.0f * x) + 1.0f);
}

// ---------------------------------------------------------------------------
// Kernel 1 (96 blocks x 512):
//   blocks 0..63 : W_e (= W_attn[:,512:]) -> bf16 into wsB with layout
//     [cb(2)][kh(2)][kt'(8)][page(4)][n(256)] x 16B, where the 16B chunk at
//     (cb,kh,kt',p,n) holds B[row cb*256+n][k = kh*256+kt'*32+s*8 .. +8] with
//     s = p ^ (n&3)  (pre-swizzled so fused stages LINEARLY via
//     global_load_lds and reads page = lhi^(llo&3) conflict-light).
//   blocks 64..95: proj1[b][e] = sum_d dh[b,d]*W_attn[e,d] + b_attn[e]
// ---------------------------------------------------------------------------
__global__ __launch_bounds__(512) void prep_kernel(
    const float* __restrict__ dh, const float* __restrict__ W_attn,
    const float* __restrict__ b_attn, unsigned short* __restrict__ wsB,
    float* __restrict__ wsP1) {
    __shared__ float dhs[512];
    const int tid = threadIdx.x;
    if (blockIdx.x < 64) {
        int idx = blockIdx.x * 512 + tid;       // 0..32767 16B-chunks
        int n  = idx & 255;
        int r  = idx >> 8;                      // 0..127
        int p  = r & 3;
        int kt = (r >> 2) & 7;
        int kh = (r >> 5) & 1;
        int cb = r >> 6;
        int s  = p ^ (n & 3);
        const float* src = W_attn + (size_t)(cb * 256 + n) * 1024 + 512 +
                           kh * 256 + kt * 32 + s * 8;
        float4 f0 = *(const float4*)(src);
        float4 f1 = *(const float4*)(src + 4);
        *(short8*)((char*)wsB + (size_t)idx * 16) = cvt8(f0, f1);
    } else {
        int b = blockIdx.x - 64;
        dhs[tid] = dh[b * 512 + tid];
        __syncthreads();
        const float* wrow = W_attn + (size_t)tid * 1024;  // W_h row e=tid
        float acc = 0.f;
        #pragma unroll 8
        for (int d = 0; d < 512; d += 4) {
            float4 w = *(const float4*)(wrow + d);
            acc += dhs[d] * w.x + dhs[d + 1] * w.y + dhs[d + 2] * w.z + dhs[d + 3] * w.w;
        }
        wsP1[b * 512 + tid] = acc + b_attn[tid];
    }
}

// ---------------------------------------------------------------------------
// Kernel 2: fused GEMM (256 rows x 256 cols per block, K=512) + tanh + v-dot.
// 1024 thr = 16 waves (4M x 4N); wave tile 64x64 = 4x4 frags of 16x16x32.
// NO BARRIERS in the K-loop:
//   - B: static 128 KB LDS per K-half, staged twice via global_load_lds
//     (4 barriers per block total, vs 32 in the per-kt-convoy designs).
//   - A: DIRECT global->register per wave (each wave owns its rows), f32
//     loads + cvt_pk, software-pipelined by the compiler - no sync at all.
// 4 waves/SIMD free-run and hide each other's latencies (m114 regime).
// cb=0 writes partial scores to out, cb=1 to wsS1; softmax adds them.
// ---------------------------------------------------------------------------
__global__ __launch_bounds__(1024, 4) void fused_kernel(
    const float* __restrict__ enc, const unsigned short* __restrict__ wsB,
    const float* __restrict__ wsP1, const float* __restrict__ vvec,
    float* __restrict__ out, float* __restrict__ wsS1) {
    __shared__ char lds[135168];                 // B 128 KB | red 4 KB
    float* const red = (float*)(lds + 131072);   // [4 wc][256 rows]

    const int tid  = threadIdx.x;
    const int wave = tid >> 6;
    const int lane = tid & 63;
    const int llo  = lane & 15, lhi = lane >> 4;
    const int wr   = wave >> 2, wc = wave & 3;

    // XCD-chunked bijective swizzle (1024 % 8 == 0). Partner blocks
    // (cb=0/1, same rows) are consecutive lb -> same XCD chunk -> enc L2-hot.
    const int bid = blockIdx.x;
    const int lb  = (bid & 7) * 128 + (bid >> 3);
    const int rb  = lb >> 1, cb = lb & 1;
    const int m0  = rb * 256;
    const int b   = m0 >> 12;                    // batch (256 | 4096)

    // A-direct base: lane (llo,lhi) of frag mi at ktg reads
    // enc[m0 + wr*64 + mi*16 + llo][ktg*32 + lhi*8 .. +8]  (2 x float4)
    const float* abase = enc + (size_t)(m0 + wr * 64 + llo) * 512 + lhi * 8;

    // B frag (ni) at kt' (within half): n = wc*64 + ni*16 + llo, k-slot lhi,
    // stored at page lhi^(llo&3):
    const int bfbase = ((lhi ^ (llo & 3)) << 12) + ((wc * 64 + llo) << 4);
    const char* const bls = lds;

    f32x4 acc[4][4] = {};
    float4 ra0, ra1, ra2, ra3;

    #define ALOAD(mi, ktg, RA, RB)                                    \
        do { const float* p_ = abase + (mi) * 8192 + (ktg) * 32;      \
             RA = *(const float4*)(p_);                               \
             RB = *(const float4*)(p_ + 4); } while (0)

    #define GLDS_B(kh)                                                             \
        do { const char* bsrc_ = (const char*)wsB + cb * 262144 + (kh) * 131072;   \
             _Pragma("unroll")                                                     \
             for (int i_ = 0; i_ < 8; ++i_) {                                      \
                 int off_ = (i_ * 1024 + tid) * 16;                                \
                 __builtin_amdgcn_global_load_lds(                                 \
                     (const uint32_t __attribute__((address_space(1)))*)(bsrc_ + off_), \
                     (uint32_t __attribute__((address_space(3)))*)(lds + (i_ * 1024 + tid) * 16), \
                     16, 0, 0);                                                    \
             } } while (0)

    // One K-step: ktp = kt within half (B addr), ktg = global kt (A addr).
    // On entry ra0..ra3 hold f32 for frags 0,1 of THIS ktg.
    #define KT_BODY(ktp, ktg, LAST)                                                \
        do {                                                                       \
            short8 af0 = cvt8(ra0, ra1), af1 = cvt8(ra2, ra3);                     \
            ALOAD(2, ktg, ra0, ra1); ALOAD(3, ktg, ra2, ra3);                      \
            short8 bf0 = *(const short8*)(bls + bfbase + (ktp) * 16384);           \
            short8 bf1 = *(const short8*)(bls + bfbase + (ktp) * 16384 + 256);     \
            short8 bf2 = *(const short8*)(bls + bfbase + (ktp) * 16384 + 512);     \
            short8 bf3 = *(const short8*)(bls + bfbase + (ktp) * 16384 + 768);     \
            acc[0][0] = __builtin_amdgcn_mfma_f32_16x16x32_bf16(af0, bf0, acc[0][0], 0, 0, 0); \
            acc[0][1] = __builtin_amdgcn_mfma_f32_16x16x32_bf16(af0, bf1, acc[0][1], 0, 0, 0); \
            acc[0][2] = __builtin_amdgcn_mfma_f32_16x16x32_bf16(af0, bf2, acc[0][2], 0, 0, 0); \
            acc[0][3] = __builtin_amdgcn_mfma_f32_16x16x32_bf16(af0, bf3, acc[0][3], 0, 0, 0); \
            acc[1][0] = __builtin_amdgcn_mfma_f32_16x16x32_bf16(af1, bf0, acc[1][0], 0, 0, 0); \
            acc[1][1] = __builtin_amdgcn_mfma_f32_16x16x32_bf16(af1, bf1, acc[1][1], 0, 0, 0); \
            acc[1][2] = __builtin_amdgcn_mfma_f32_16x16x32_bf16(af1, bf2, acc[1][2], 0, 0, 0); \
            acc[1][3] = __builtin_amdgcn_mfma_f32_16x16x32_bf16(af1, bf3, acc[1][3], 0, 0, 0); \
            short8 af2 = cvt8(ra0, ra1), af3 = cvt8(ra2, ra3);                     \
            if (!(LAST)) { ALOAD(0, (ktg) + 1, ra0, ra1); ALOAD(1, (ktg) + 1, ra2, ra3); } \
            acc[2][0] = __builtin_amdgcn_mfma_f32_16x16x32_bf16(af2, bf0, acc[2][0], 0, 0, 0); \
            acc[2][1] = __builtin_amdgcn_mfma_f32_16x16x32_bf16(af2, bf1, acc[2][1], 0, 0, 0); \
            acc[2][2] = __builtin_amdgcn_mfma_f32_16x16x32_bf16(af2, bf2, acc[2][2], 0, 0, 0); \
            acc[2][3] = __builtin_amdgcn_mfma_f32_16x16x32_bf16(af2, bf3, acc[2][3], 0, 0, 0); \
            acc[3][0] = __builtin_amdgcn_mfma_f32_16x16x32_bf16(af3, bf0, acc[3][0], 0, 0, 0); \
            acc[3][1] = __builtin_amdgcn_mfma_f32_16x16x32_bf16(af3, bf1, acc[3][1], 0, 0, 0); \
            acc[3][2] = __builtin_amdgcn_mfma_f32_16x16x32_bf16(af3, bf2, acc[3][2], 0, 0, 0); \
            acc[3][3] = __builtin_amdgcn_mfma_f32_16x16x32_bf16(af3, bf3, acc[3][3], 0, 0, 0); \
        } while (0)

    // ---- prologue: A frags 0,1 of kt 0 in flight; stage B half 0 ----
    ALOAD(0, 0, ra0, ra1); ALOAD(1, 0, ra2, ra3);
    GLDS_B(0);
    __syncthreads();

    // ---- K half 0 (ktg 0..7): barrier-free free-run ----
    KT_BODY(0, 0, 0); KT_BODY(1, 1, 0); KT_BODY(2, 2, 0); KT_BODY(3, 3, 0);
    KT_BODY(4, 4, 0); KT_BODY(5, 5, 0); KT_BODY(6, 6, 0); KT_BODY(7, 7, 0);

    __syncthreads();          // all waves done reading B half 0
    GLDS_B(1);
    __syncthreads();          // B half 1 ready

    // ---- K half 1 (ktg 8..15) ----
    KT_BODY(0, 8, 0);  KT_BODY(1, 9, 0);  KT_BODY(2, 10, 0); KT_BODY(3, 11, 0);
    KT_BODY(4, 12, 0); KT_BODY(5, 13, 0); KT_BODY(6, 14, 0); KT_BODY(7, 15, 1);

    // --- epilogue: tanh(acc + proj1[b,d]) * v[d], partial-reduce over d ---
    float p1v[4], vv[4];
    #pragma unroll
    for (int ni = 0; ni < 4; ++ni) {
        int d = cb * 256 + wc * 64 + ni * 16 + llo;
        p1v[ni] = wsP1[b * 512 + d];
        vv[ni]  = vvec[d];
    }
    float part[16];
    #pragma unroll
    for (int mi = 0; mi < 4; ++mi)
        #pragma unroll
        for (int r = 0; r < 4; ++r) {
            float s = 0.f;
            #pragma unroll
            for (int ni = 0; ni < 4; ++ni)
                s += tanh_fast(acc[mi][ni][r] + p1v[ni]) * vv[ni];
            part[mi * 4 + r] = s;
        }
    // reduce over the 16 columns held by the llo lane group (lane bits 0..3)
    #pragma unroll
    for (int off = 1; off < 16; off <<= 1)
        #pragma unroll
        for (int i = 0; i < 16; ++i)
            part[i] += __shfl_xor(part[i], off, 64);

    if (llo == 0) {
        #pragma unroll
        for (int mi = 0; mi < 4; ++mi)
            #pragma unroll
            for (int r = 0; r < 4; ++r)
                red[wc * 256 + wr * 64 + mi * 16 + lhi * 4 + r] = part[mi * 4 + r];
    }
    __syncthreads();
    if (tid < 256) {
        float s = red[tid] + red[256 + tid] + red[512 + tid] + red[768 + tid];
        (cb ? wsS1 : out)[m0 + tid] = s;
    }
}

// ---------------------------------------------------------------------------
// Kernel 3: add the two column-half partials, row softmax over S=4096,
// write to out. 32 blocks x 256.
// ---------------------------------------------------------------------------
__global__ __launch_bounds__(256) void softmax_kernel(
    float* __restrict__ out, const float* __restrict__ wsS1) {
    __shared__ float wred[8];
    const int b = blockIdx.x, tid = threadIdx.x;
    float* row = out + (size_t)b * 4096;
    const float* row1 = wsS1 + (size_t)b * 4096;
    float vals[16];
    float lmax = -1e30f;
    #pragma unroll
    for (int i = 0; i < 16; ++i) {
        vals[i] = row[i * 256 + tid] + row1[i * 256 + tid];
        lmax = fmaxf(lmax, vals[i]);
    }
    #pragma unroll
    for (int off = 32; off >= 1; off >>= 1)
        lmax = fmaxf(lmax, __shfl_xor(lmax, off, 64));
    if ((tid & 63) == 0) wred[tid >> 6] = lmax;
    __syncthreads();
    float gmax = fmaxf(fmaxf(wred[0], wred[1]), fmaxf(wred[2], wred[3]));
    float lsum = 0.f;
    #pragma unroll
    for (int i = 0; i < 16; ++i) {
        vals[i] = expf(vals[i] - gmax);
        lsum += vals[i];
    }
    #pragma unroll
    for (int off = 32; off >= 1; off >>= 1)
        lsum += __shfl_xor(lsum, off, 64);
    if ((tid & 63) == 0) wred[4 + (tid >> 6)] = lsum;
    __syncthreads();
    float inv = 1.f / (wred[4] + wred[5] + wred[6] + wred[7]);
    #pragma unroll
    for (int i = 0; i < 16; ++i)
        row[i * 256 + tid] = vals[i] * inv;
}

extern "C" void kernel_launch(void* const* d_in, const int* in_sizes, int n_in,
                              void* d_out, int out_size, void* d_ws, size_t ws_size,
                              hipStream_t stream) {
    const float* dh   = (const float*)d_in[0];   // (32, 512)
    const float* enc  = (const float*)d_in[1];   // (32, 4096, 512)
    const float* Wat  = (const float*)d_in[2];   // (512, 1024)
    const float* batt = (const float*)d_in[3];   // (512,)
    const float* vvec = (const float*)d_in[4];   // (512,)
    float* out = (float*)d_out;                  // (32, 4096)

    unsigned short* wsB = (unsigned short*)d_ws;               // 512 KB bf16 W_e
    float* wsP1 = (float*)((char*)d_ws + 524288);              // 64 KB proj1
    float* wsS1 = (float*)((char*)d_ws + 589824);              // 512 KB partial

    hipLaunchKernelGGL(prep_kernel, dim3(96), dim3(512), 0, stream,
                       dh, Wat, batt, wsB, wsP1);
    hipLaunchKernelGGL(fused_kernel, dim3(1024), dim3(1024), 0, stream,
                       enc, wsB, wsP1, vvec, out, wsS1);
    hipLaunchKernelGGL(softmax_kernel, dim3(32), dim3(256), 0, stream, out, wsS1);
}